// Round 1
// baseline (988.150 us; speedup 1.0000x reference)
//
#include <hip/hip_runtime.h>
#include <math.h>

#define NEG_SLOPE 0.2f

// ---- monotone float<->uint encoding for atomicMax on floats ----
__device__ __forceinline__ unsigned enc_f(float f) {
    unsigned b = __float_as_uint(f);
    return (b & 0x80000000u) ? ~b : (b | 0x80000000u);
}
__device__ __forceinline__ float dec_f(unsigned u) {
    unsigned b = (u & 0x80000000u) ? (u & 0x7fffffffu) : ~u;
    return __uint_as_float(b);
}

// ---- h = act(X [+bias]) @ W ; asrc = h@a_src ; adst = h@a_dst ----
// relu_bias=0: h = X @ W            (layer 1: raw features)
// relu_bias=1: h = relu(X + b) @ W  (layer 2: consumes previous agg + bias)
__global__ __launch_bounds__(256) void gemm_attn(
    const float* __restrict__ X, const float* __restrict__ W,
    const float* __restrict__ av_s, const float* __restrict__ av_d,
    const float* __restrict__ bias, int relu_bias,
    float* __restrict__ H, float* __restrict__ Asrc, float* __restrict__ Adst,
    int n)
{
    __shared__ float Ws[64 * 64];
    __shared__ float as_s[64], ad_s[64], b_s[64];
    int t = threadIdx.x;
    for (int i = t; i < 64 * 64; i += 256) Ws[i] = W[i];
    if (t < 64) { as_s[t] = av_s[t]; ad_s[t] = av_d[t]; b_s[t] = bias[t]; }
    __syncthreads();

    int row = blockIdx.x * 256 + t;
    if (row >= n) return;

    const float* xp = X + (size_t)row * 64;
    float xr[64];
    #pragma unroll
    for (int k = 0; k < 64; k += 4) {
        float4 v = *reinterpret_cast<const float4*>(xp + k);
        if (relu_bias) {
            v.x = fmaxf(v.x + b_s[k],     0.f);
            v.y = fmaxf(v.y + b_s[k + 1], 0.f);
            v.z = fmaxf(v.z + b_s[k + 2], 0.f);
            v.w = fmaxf(v.w + b_s[k + 3], 0.f);
        }
        xr[k] = v.x; xr[k + 1] = v.y; xr[k + 2] = v.z; xr[k + 3] = v.w;
    }

    float ss = 0.f, sd = 0.f;
    float* hp = H + (size_t)row * 64;
    #pragma unroll 1
    for (int j = 0; j < 64; j += 4) {
        float a0 = 0.f, a1 = 0.f, a2 = 0.f, a3 = 0.f;
        #pragma unroll
        for (int k = 0; k < 64; k++) {
            float4 w = *reinterpret_cast<const float4*>(&Ws[k * 64 + j]);
            a0 += xr[k] * w.x; a1 += xr[k] * w.y;
            a2 += xr[k] * w.z; a3 += xr[k] * w.w;
        }
        float4 o; o.x = a0; o.y = a1; o.z = a2; o.w = a3;
        *reinterpret_cast<float4*>(hp + j) = o;
        ss += a0 * as_s[j] + a1 * as_s[j + 1] + a2 * as_s[j + 2] + a3 * as_s[j + 3];
        sd += a0 * ad_s[j] + a1 * ad_s[j + 1] + a2 * ad_s[j + 2] + a3 * ad_s[j + 3];
    }
    Asrc[row] = ss;
    Adst[row] = sd;
}

// ---- per-edge segment max (bit-encoded atomicMax) ----
__global__ __launch_bounds__(256) void edge_max_k(
    const int* __restrict__ ei, const float* __restrict__ Asrc,
    const float* __restrict__ Adst, unsigned* __restrict__ m_enc,
    int E, int EN)
{
    int e = blockIdx.x * 256 + threadIdx.x;
    if (e >= EN) return;
    int s, d;
    if (e < E) { s = ei[e]; d = ei[E + e]; } else { s = e - E; d = s; }
    float l = Asrc[s] + Adst[d];
    l = l > 0.f ? l : NEG_SLOPE * l;
    atomicMax(&m_enc[d], enc_f(l));
}

// ---- per-edge exp + segment sum (denominator) ----
__global__ __launch_bounds__(256) void edge_denom_k(
    const int* __restrict__ ei, const float* __restrict__ Asrc,
    const float* __restrict__ Adst, const unsigned* __restrict__ m_enc,
    float* __restrict__ denom, int E, int EN)
{
    int e = blockIdx.x * 256 + threadIdx.x;
    if (e >= EN) return;
    int s, d;
    if (e < E) { s = ei[e]; d = ei[E + e]; } else { s = e - E; d = s; }
    float l = Asrc[s] + Adst[d];
    l = l > 0.f ? l : NEG_SLOPE * l;
    float ex = __expf(l - dec_f(m_enc[d]));
    atomicAdd(&denom[d], ex);
}

// ---- wave-per-edge feature scatter: agg[dst] += alpha * h[src] ----
__global__ __launch_bounds__(256) void edge_scatter_k(
    const int* __restrict__ ei, const float* __restrict__ Asrc,
    const float* __restrict__ Adst, const unsigned* __restrict__ m_enc,
    const float* __restrict__ denom, const float* __restrict__ H,
    float* __restrict__ agg, int E, int EN)
{
    int wid = blockIdx.x * 4 + (threadIdx.x >> 6);  // 4 waves/block, 1 edge/wave
    int lane = threadIdx.x & 63;
    if (wid >= EN) return;
    int s, d;
    if (wid < E) { s = ei[wid]; d = ei[E + wid]; } else { s = wid - E; d = s; }
    float l = Asrc[s] + Adst[d];
    l = l > 0.f ? l : NEG_SLOPE * l;
    float alpha = __expf(l - dec_f(m_enc[d])) / (denom[d] + 1e-16f);
    atomicAdd(&agg[(size_t)d * 64 + lane], alpha * H[(size_t)s * 64 + lane]);
}

// ---- classifier: relu(agg + b2) @ Wc + bc, then log_softmax over 2 classes ----
__global__ __launch_bounds__(256) void classifier_k(
    const float* __restrict__ agg, const float* __restrict__ bias,
    const float* __restrict__ Wc, const float* __restrict__ bc,
    float* __restrict__ out, int n)
{
    __shared__ float Wcs[128], bs[64], bcs[2];
    int t = threadIdx.x;
    if (t < 128) Wcs[t] = Wc[t];
    if (t < 64) bs[t] = bias[t];
    if (t < 2) bcs[t] = bc[t];
    __syncthreads();

    int row = blockIdx.x * 256 + t;
    if (row >= n) return;
    const float* ap = agg + (size_t)row * 64;
    float z0 = bcs[0], z1 = bcs[1];
    #pragma unroll
    for (int k = 0; k < 64; k++) {
        float h = fmaxf(ap[k] + bs[k], 0.f);
        z0 += h * Wcs[2 * k];
        z1 += h * Wcs[2 * k + 1];
    }
    float m = fmaxf(z0, z1);
    float lse = m + logf(__expf(z0 - m) + __expf(z1 - m));
    out[(size_t)row * 2]     = z0 - lse;
    out[(size_t)row * 2 + 1] = z1 - lse;
}

extern "C" void kernel_launch(void* const* d_in, const int* in_sizes, int n_in,
                              void* d_out, int out_size, void* d_ws, size_t ws_size,
                              hipStream_t stream)
{
    const float* x   = (const float*)d_in[0];
    const int*   ei  = (const int*)d_in[1];
    const float* W1  = (const float*)d_in[2];
    const float* as1 = (const float*)d_in[3];
    const float* ad1 = (const float*)d_in[4];
    const float* b1  = (const float*)d_in[5];
    const float* W2  = (const float*)d_in[6];
    const float* as2 = (const float*)d_in[7];
    const float* ad2 = (const float*)d_in[8];
    const float* b2  = (const float*)d_in[9];
    const float* Wc  = (const float*)d_in[10];
    const float* bc  = (const float*)d_in[11];
    float* out = (float*)d_out;

    const int N  = in_sizes[0] / 64;   // 100000
    const int E  = in_sizes[1] / 2;    // 1200000
    const int EN = E + N;              // edges incl. self loops

    // workspace layout (fp32): h[N*64] | agg[N*64] | asrc[N] | adst[N] | m_enc[N] | denom[N]
    float* h    = (float*)d_ws;
    float* agg  = h + (size_t)N * 64;
    float* asrc = agg + (size_t)N * 64;
    float* adst = asrc + N;
    unsigned* m_enc = (unsigned*)(adst + N);
    float* denom = (float*)(m_enc + N);

    const int gN = (N + 255) / 256;
    const int gE = (EN + 255) / 256;
    const int gS = (EN + 3) / 4;       // 4 edges (waves) per 256-thread block

    // ---------------- layer 1 ----------------
    gemm_attn<<<gN, 256, 0, stream>>>(x, W1, as1, ad1, b1, 0, h, asrc, adst, N);
    hipMemsetAsync(agg,   0, (size_t)N * 64 * sizeof(float), stream);
    hipMemsetAsync(m_enc, 0, (size_t)N * sizeof(unsigned),   stream);
    hipMemsetAsync(denom, 0, (size_t)N * sizeof(float),      stream);
    edge_max_k    <<<gE, 256, 0, stream>>>(ei, asrc, adst, m_enc, E, EN);
    edge_denom_k  <<<gE, 256, 0, stream>>>(ei, asrc, adst, m_enc, denom, E, EN);
    edge_scatter_k<<<gS, 256, 0, stream>>>(ei, asrc, adst, m_enc, denom, h, agg, E, EN);

    // ---------------- layer 2 (bias+relu of layer 1 fused into GEMM load) ----------------
    gemm_attn<<<gN, 256, 0, stream>>>(agg, W2, as2, ad2, b1, 1, h, asrc, adst, N);
    hipMemsetAsync(agg,   0, (size_t)N * 64 * sizeof(float), stream);
    hipMemsetAsync(m_enc, 0, (size_t)N * sizeof(unsigned),   stream);
    hipMemsetAsync(denom, 0, (size_t)N * sizeof(float),      stream);
    edge_max_k    <<<gE, 256, 0, stream>>>(ei, asrc, adst, m_enc, E, EN);
    edge_denom_k  <<<gE, 256, 0, stream>>>(ei, asrc, adst, m_enc, denom, E, EN);
    edge_scatter_k<<<gS, 256, 0, stream>>>(ei, asrc, adst, m_enc, denom, h, agg, E, EN);

    // ---------------- classifier ----------------
    classifier_k<<<gN, 256, 0, stream>>>(agg, b2, Wc, bc, out, N);
}

// Round 2
// 449.981 us; speedup vs baseline: 2.1960x; 2.1960x over previous
//
#include <hip/hip_runtime.h>
#include <math.h>

#define NEG_SLOPE 0.2f

// ============================================================
// CSR build: count -> scan (3 kernels) -> fill
// ============================================================

__global__ __launch_bounds__(256) void count_k(
    const int* __restrict__ ei, int* __restrict__ deg, int E, int EN)
{
    int e = blockIdx.x * 256 + threadIdx.x;
    if (e >= EN) return;
    int d = (e < E) ? ei[E + e] : (e - E);
    atomicAdd(&deg[d], 1);
}

// block scans 1024 elements (256 threads x 4)
__global__ __launch_bounds__(256) void scan1_k(
    const int* __restrict__ deg, int* __restrict__ partial,
    int* __restrict__ bsum, int n)
{
    __shared__ int lds[256];
    int t = threadIdx.x;
    int base = blockIdx.x * 1024 + t * 4;
    int v0 = (base + 0 < n) ? deg[base + 0] : 0;
    int v1 = (base + 1 < n) ? deg[base + 1] : 0;
    int v2 = (base + 2 < n) ? deg[base + 2] : 0;
    int v3 = (base + 3 < n) ? deg[base + 3] : 0;
    int s = v0 + v1 + v2 + v3;
    lds[t] = s;
    __syncthreads();
    for (int o = 1; o < 256; o <<= 1) {
        int x = (t >= o) ? lds[t - o] : 0;
        __syncthreads();
        lds[t] += x;
        __syncthreads();
    }
    int excl = lds[t] - s;
    if (t == 255) bsum[blockIdx.x] = lds[255];
    if (base + 0 < n) partial[base + 0] = excl;
    if (base + 1 < n) partial[base + 1] = excl + v0;
    if (base + 2 < n) partial[base + 2] = excl + v0 + v1;
    if (base + 3 < n) partial[base + 3] = excl + v0 + v1 + v2;
}

// single block, in-place exclusive scan of up to 1024 block sums
__global__ __launch_bounds__(256) void scan2_k(int* __restrict__ bsum, int nb)
{
    __shared__ int lds[256];
    int t = threadIdx.x;
    int base = t * 4;
    int v0 = (base + 0 < nb) ? bsum[base + 0] : 0;
    int v1 = (base + 1 < nb) ? bsum[base + 1] : 0;
    int v2 = (base + 2 < nb) ? bsum[base + 2] : 0;
    int v3 = (base + 3 < nb) ? bsum[base + 3] : 0;
    int s = v0 + v1 + v2 + v3;
    lds[t] = s;
    __syncthreads();
    for (int o = 1; o < 256; o <<= 1) {
        int x = (t >= o) ? lds[t - o] : 0;
        __syncthreads();
        lds[t] += x;
        __syncthreads();
    }
    int excl = lds[t] - s;
    if (base + 0 < nb) bsum[base + 0] = excl;
    if (base + 1 < nb) bsum[base + 1] = excl + v0;
    if (base + 2 < nb) bsum[base + 2] = excl + v0 + v1;
    if (base + 3 < nb) bsum[base + 3] = excl + v0 + v1 + v2;
}

__global__ __launch_bounds__(256) void scan3_k(
    const int* __restrict__ partial, const int* __restrict__ bsum,
    int* __restrict__ rowptr, int* __restrict__ cursor, int n, int EN)
{
    int i = blockIdx.x * 256 + threadIdx.x;
    if (i == 0) rowptr[n] = EN;
    if (i >= n) return;
    int r = partial[i] + bsum[i >> 10];
    rowptr[i] = r;
    cursor[i] = r;
}

__global__ __launch_bounds__(256) void fill_k(
    const int* __restrict__ ei, int* __restrict__ cursor,
    int* __restrict__ col, int E, int EN)
{
    int e = blockIdx.x * 256 + threadIdx.x;
    if (e >= EN) return;
    int s, d;
    if (e < E) { s = ei[e]; d = ei[E + e]; } else { s = e - E; d = s; }
    int pos = atomicAdd(&cursor[d], 1);
    col[pos] = s;
}

// ============================================================
// h = act(X [+bias]) @ W ; asrc = h@a_src ; adst = h@a_dst
// ============================================================
__global__ __launch_bounds__(256) void gemm_attn(
    const float* __restrict__ X, const float* __restrict__ W,
    const float* __restrict__ av_s, const float* __restrict__ av_d,
    const float* __restrict__ bias, int relu_bias,
    float* __restrict__ H, float* __restrict__ Asrc, float* __restrict__ Adst,
    int n)
{
    __shared__ float Ws[64 * 64];
    __shared__ float as_s[64], ad_s[64], b_s[64];
    int t = threadIdx.x;
    for (int i = t; i < 64 * 64; i += 256) Ws[i] = W[i];
    if (t < 64) { as_s[t] = av_s[t]; ad_s[t] = av_d[t]; b_s[t] = bias[t]; }
    __syncthreads();

    int row = blockIdx.x * 256 + t;
    if (row >= n) return;

    const float* xp = X + (size_t)row * 64;
    float xr[64];
    #pragma unroll
    for (int k = 0; k < 64; k += 4) {
        float4 v = *reinterpret_cast<const float4*>(xp + k);
        if (relu_bias) {
            v.x = fmaxf(v.x + b_s[k],     0.f);
            v.y = fmaxf(v.y + b_s[k + 1], 0.f);
            v.z = fmaxf(v.z + b_s[k + 2], 0.f);
            v.w = fmaxf(v.w + b_s[k + 3], 0.f);
        }
        xr[k] = v.x; xr[k + 1] = v.y; xr[k + 2] = v.z; xr[k + 3] = v.w;
    }

    float ss = 0.f, sd = 0.f;
    float* hp = H + (size_t)row * 64;
    #pragma unroll 1
    for (int j = 0; j < 64; j += 4) {
        float a0 = 0.f, a1 = 0.f, a2 = 0.f, a3 = 0.f;
        #pragma unroll
        for (int k = 0; k < 64; k++) {
            float4 w = *reinterpret_cast<const float4*>(&Ws[k * 64 + j]);
            a0 += xr[k] * w.x; a1 += xr[k] * w.y;
            a2 += xr[k] * w.z; a3 += xr[k] * w.w;
        }
        float4 o; o.x = a0; o.y = a1; o.z = a2; o.w = a3;
        *reinterpret_cast<float4*>(hp + j) = o;
        ss += a0 * as_s[j] + a1 * as_s[j + 1] + a2 * as_s[j + 2] + a3 * as_s[j + 3];
        sd += a0 * ad_s[j] + a1 * ad_s[j + 1] + a2 * ad_s[j + 2] + a3 * ad_s[j + 3];
    }
    Asrc[row] = ss;
    Adst[row] = sd;
}

// ============================================================
// pull aggregation: one wave per dst node, lane = feature
// phase A: segment max + denom (lanes parallel over in-edges)
// phase B: acc[lane] += alpha_e * H[src_e][lane], serial over edges
//          (alphas/srcs staged through LDS in chunks of 64)
// ============================================================
__global__ __launch_bounds__(256) void node_agg_k(
    const int* __restrict__ rowptr, const int* __restrict__ col,
    const float* __restrict__ Asrc, const float* __restrict__ Adst,
    const float* __restrict__ H, float* __restrict__ agg, int n)
{
    __shared__ float lds_a[4][64];
    __shared__ int   lds_s[4][64];
    int wi   = threadIdx.x >> 6;
    int lane = threadIdx.x & 63;
    int w = blockIdx.x * 4 + wi;
    if (w >= n) return;

    int beg = rowptr[w];
    int end = rowptr[w + 1];
    float adst = Adst[w];

    // ---- phase A: max ----
    float m = -3.4e38f;
    for (int i = beg + lane; i < end; i += 64) {
        float l = Asrc[col[i]] + adst;
        l = l > 0.f ? l : NEG_SLOPE * l;
        m = fmaxf(m, l);
    }
    #pragma unroll
    for (int o = 32; o; o >>= 1) m = fmaxf(m, __shfl_xor(m, o, 64));

    // ---- phase A: denom ----
    float den = 0.f;
    for (int i = beg + lane; i < end; i += 64) {
        float l = Asrc[col[i]] + adst;
        l = l > 0.f ? l : NEG_SLOPE * l;
        den += __expf(l - m);
    }
    #pragma unroll
    for (int o = 32; o; o >>= 1) den += __shfl_xor(den, o, 64);
    float inv = 1.f / (den + 1e-16f);

    // ---- phase B: feature accumulation ----
    float acc = 0.f;
    for (int cbeg = beg; cbeg < end; cbeg += 64) {
        int cnt = min(64, end - cbeg);
        int i = cbeg + lane;
        if (lane < cnt) {
            int s = col[i];
            float l = Asrc[s] + adst;
            l = l > 0.f ? l : NEG_SLOPE * l;
            lds_a[wi][lane] = __expf(l - m) * inv;
            lds_s[wi][lane] = s;
        }
        // wave-synchronous LDS use (single wave writes+reads its own slice)
        for (int j = 0; j < cnt; j++) {
            float a = lds_a[wi][j];
            int   s = lds_s[wi][j];
            acc += a * H[(size_t)s * 64 + lane];
        }
    }
    agg[(size_t)w * 64 + lane] = acc;
}

// ============================================================
// classifier: relu(agg + b2) @ Wc + bc -> log_softmax (C=2)
// ============================================================
__global__ __launch_bounds__(256) void classifier_k(
    const float* __restrict__ agg, const float* __restrict__ bias,
    const float* __restrict__ Wc, const float* __restrict__ bc,
    float* __restrict__ out, int n)
{
    __shared__ float Wcs[128], bs[64], bcs[2];
    int t = threadIdx.x;
    if (t < 128) Wcs[t] = Wc[t];
    if (t < 64) bs[t] = bias[t];
    if (t < 2) bcs[t] = bc[t];
    __syncthreads();

    int row = blockIdx.x * 256 + t;
    if (row >= n) return;
    const float* ap = agg + (size_t)row * 64;
    float z0 = bcs[0], z1 = bcs[1];
    #pragma unroll
    for (int k = 0; k < 64; k++) {
        float h = fmaxf(ap[k] + bs[k], 0.f);
        z0 += h * Wcs[2 * k];
        z1 += h * Wcs[2 * k + 1];
    }
    float m = fmaxf(z0, z1);
    float lse = m + logf(__expf(z0 - m) + __expf(z1 - m));
    out[(size_t)row * 2]     = z0 - lse;
    out[(size_t)row * 2 + 1] = z1 - lse;
}

extern "C" void kernel_launch(void* const* d_in, const int* in_sizes, int n_in,
                              void* d_out, int out_size, void* d_ws, size_t ws_size,
                              hipStream_t stream)
{
    const float* x   = (const float*)d_in[0];
    const int*   ei  = (const int*)d_in[1];
    const float* W1  = (const float*)d_in[2];
    const float* as1 = (const float*)d_in[3];
    const float* ad1 = (const float*)d_in[4];
    const float* b1  = (const float*)d_in[5];
    const float* W2  = (const float*)d_in[6];
    const float* as2 = (const float*)d_in[7];
    const float* ad2 = (const float*)d_in[8];
    const float* b2  = (const float*)d_in[9];
    const float* Wc  = (const float*)d_in[10];
    const float* bc  = (const float*)d_in[11];
    float* out = (float*)d_out;

    const int N  = in_sizes[0] / 64;   // 100000
    const int E  = in_sizes[1] / 2;    // 1200000
    const int EN = E + N;

    // workspace layout (all 4B elems):
    // h[N*64] | agg[N*64] | asrc[N] | adst[N] | deg[N] | partial[N] |
    // rowptr[N+1] | cursor[N] | bsum[1024] | col[EN]
    float* h    = (float*)d_ws;
    float* agg  = h + (size_t)N * 64;
    float* asrc = agg + (size_t)N * 64;
    float* adst = asrc + N;
    int* deg     = (int*)(adst + N);
    int* partial = deg + N;
    int* rowptr  = partial + N;
    int* cursor  = rowptr + (N + 1);
    int* bsum    = cursor + N;
    int* col     = bsum + 1024;

    const int gN  = (N + 255) / 256;
    const int gE  = (EN + 255) / 256;
    const int gSc = (N + 1023) / 1024;   // scan blocks (1024 elems each)
    const int gW  = (N + 3) / 4;         // 4 waves (nodes) per block

    // ---------------- CSR build (shared by both layers) ----------------
    hipMemsetAsync(deg, 0, (size_t)N * sizeof(int), stream);
    count_k<<<gE, 256, 0, stream>>>(ei, deg, E, EN);
    scan1_k<<<gSc, 256, 0, stream>>>(deg, partial, bsum, N);
    scan2_k<<<1, 256, 0, stream>>>(bsum, gSc);
    scan3_k<<<gN, 256, 0, stream>>>(partial, bsum, rowptr, cursor, N, EN);
    fill_k<<<gE, 256, 0, stream>>>(ei, cursor, col, E, EN);

    // ---------------- layer 1 ----------------
    gemm_attn<<<gN, 256, 0, stream>>>(x, W1, as1, ad1, b1, 0, h, asrc, adst, N);
    node_agg_k<<<gW, 256, 0, stream>>>(rowptr, col, asrc, adst, h, agg, N);

    // ---------------- layer 2 ----------------
    gemm_attn<<<gN, 256, 0, stream>>>(agg, W2, as2, ad2, b1, 1, h, asrc, adst, N);
    node_agg_k<<<gW, 256, 0, stream>>>(rowptr, col, asrc, adst, h, agg, N);

    // ---------------- classifier ----------------
    classifier_k<<<gN, 256, 0, stream>>>(agg, b2, Wc, bc, out, N);
}

// Round 3
// 353.588 us; speedup vs baseline: 2.7946x; 1.2726x over previous
//
#include <hip/hip_runtime.h>
#include <math.h>

#define NEG_SLOPE 0.2f

// ============================================================
// CSR build: count+rank -> scan (3 kernels) -> atomic-free fill
// ============================================================

__global__ __launch_bounds__(256) void count_rank_k(
    const int* __restrict__ ei, int* __restrict__ deg, int* __restrict__ rank,
    int E, int EN)
{
    int e = blockIdx.x * 256 + threadIdx.x;
    if (e >= EN) return;
    int d = (e < E) ? ei[E + e] : (e - E);
    rank[e] = atomicAdd(&deg[d], 1);   // coalesced rank store; no downstream dep
}

// block scans 1024 elements (256 threads x 4)
__global__ __launch_bounds__(256) void scan1_k(
    const int* __restrict__ deg, int* __restrict__ partial,
    int* __restrict__ bsum, int n)
{
    __shared__ int lds[256];
    int t = threadIdx.x;
    int base = blockIdx.x * 1024 + t * 4;
    int v0 = (base + 0 < n) ? deg[base + 0] : 0;
    int v1 = (base + 1 < n) ? deg[base + 1] : 0;
    int v2 = (base + 2 < n) ? deg[base + 2] : 0;
    int v3 = (base + 3 < n) ? deg[base + 3] : 0;
    int s = v0 + v1 + v2 + v3;
    lds[t] = s;
    __syncthreads();
    for (int o = 1; o < 256; o <<= 1) {
        int x = (t >= o) ? lds[t - o] : 0;
        __syncthreads();
        lds[t] += x;
        __syncthreads();
    }
    int excl = lds[t] - s;
    if (t == 255) bsum[blockIdx.x] = lds[255];
    if (base + 0 < n) partial[base + 0] = excl;
    if (base + 1 < n) partial[base + 1] = excl + v0;
    if (base + 2 < n) partial[base + 2] = excl + v0 + v1;
    if (base + 3 < n) partial[base + 3] = excl + v0 + v1 + v2;
}

__global__ __launch_bounds__(256) void scan2_k(int* __restrict__ bsum, int nb)
{
    __shared__ int lds[256];
    int t = threadIdx.x;
    int base = t * 4;
    int v0 = (base + 0 < nb) ? bsum[base + 0] : 0;
    int v1 = (base + 1 < nb) ? bsum[base + 1] : 0;
    int v2 = (base + 2 < nb) ? bsum[base + 2] : 0;
    int v3 = (base + 3 < nb) ? bsum[base + 3] : 0;
    int s = v0 + v1 + v2 + v3;
    lds[t] = s;
    __syncthreads();
    for (int o = 1; o < 256; o <<= 1) {
        int x = (t >= o) ? lds[t - o] : 0;
        __syncthreads();
        lds[t] += x;
        __syncthreads();
    }
    int excl = lds[t] - s;
    if (base + 0 < nb) bsum[base + 0] = excl;
    if (base + 1 < nb) bsum[base + 1] = excl + v0;
    if (base + 2 < nb) bsum[base + 2] = excl + v0 + v1;
    if (base + 3 < nb) bsum[base + 3] = excl + v0 + v1 + v2;
}

__global__ __launch_bounds__(256) void scan3_k(
    const int* __restrict__ partial, const int* __restrict__ bsum,
    int* __restrict__ rowptr, int n, int EN)
{
    int i = blockIdx.x * 256 + threadIdx.x;
    if (i == 0) rowptr[n] = EN;
    if (i >= n) return;
    rowptr[i] = partial[i] + bsum[i >> 10];
}

// atomic-free scatter: col[rowptr[d] + rank[e]] = s  (fire-and-forget)
__global__ __launch_bounds__(256) void fill_k(
    const int* __restrict__ ei, const int* __restrict__ rank,
    const int* __restrict__ rowptr, int* __restrict__ col, int E, int EN)
{
    int e = blockIdx.x * 256 + threadIdx.x;
    if (e >= EN) return;
    int s, d;
    if (e < E) { s = ei[e]; d = ei[E + e]; } else { s = e - E; d = s; }
    col[rowptr[d] + rank[e]] = s;
}

// ============================================================
// h = act(X [+bias]) @ W ; asrc = h@a_src ; adst = h@a_dst
// ============================================================
__global__ __launch_bounds__(256) void gemm_attn(
    const float* __restrict__ X, const float* __restrict__ W,
    const float* __restrict__ av_s, const float* __restrict__ av_d,
    const float* __restrict__ bias, int relu_bias,
    float* __restrict__ H, float* __restrict__ Asrc, float* __restrict__ Adst,
    int n)
{
    __shared__ float Ws[64 * 64];
    __shared__ float as_s[64], ad_s[64], b_s[64];
    int t = threadIdx.x;
    for (int i = t; i < 64 * 64; i += 256) Ws[i] = W[i];
    if (t < 64) { as_s[t] = av_s[t]; ad_s[t] = av_d[t]; b_s[t] = bias[t]; }
    __syncthreads();

    int row = blockIdx.x * 256 + t;
    if (row >= n) return;

    const float* xp = X + (size_t)row * 64;
    float xr[64];
    #pragma unroll
    for (int k = 0; k < 64; k += 4) {
        float4 v = *reinterpret_cast<const float4*>(xp + k);
        if (relu_bias) {
            v.x = fmaxf(v.x + b_s[k],     0.f);
            v.y = fmaxf(v.y + b_s[k + 1], 0.f);
            v.z = fmaxf(v.z + b_s[k + 2], 0.f);
            v.w = fmaxf(v.w + b_s[k + 3], 0.f);
        }
        xr[k] = v.x; xr[k + 1] = v.y; xr[k + 2] = v.z; xr[k + 3] = v.w;
    }

    float ss = 0.f, sd = 0.f;
    float* hp = H + (size_t)row * 64;
    #pragma unroll 1
    for (int j = 0; j < 64; j += 4) {
        float a0 = 0.f, a1 = 0.f, a2 = 0.f, a3 = 0.f;
        #pragma unroll
        for (int k = 0; k < 64; k++) {
            float4 w = *reinterpret_cast<const float4*>(&Ws[k * 64 + j]);
            a0 += xr[k] * w.x; a1 += xr[k] * w.y;
            a2 += xr[k] * w.z; a3 += xr[k] * w.w;
        }
        float4 o; o.x = a0; o.y = a1; o.z = a2; o.w = a3;
        *reinterpret_cast<float4*>(hp + j) = o;
        ss += a0 * as_s[j] + a1 * as_s[j + 1] + a2 * as_s[j + 2] + a3 * as_s[j + 3];
        sd += a0 * ad_s[j] + a1 * ad_s[j + 1] + a2 * ad_s[j + 2] + a3 * ad_s[j + 3];
    }
    Asrc[row] = ss;
    Adst[row] = sd;
}

// ============================================================
// pull aggregation: one wave per dst node, lane = feature.
// Fast path (deg <= 64, ~always): ONE Asrc gather per edge,
// softmax in registers, (alpha,src) broadcast via shuffle.
// ============================================================
__global__ __launch_bounds__(256) void node_agg_k(
    const int* __restrict__ rowptr, const int* __restrict__ col,
    const float* __restrict__ Asrc, const float* __restrict__ Adst,
    const float* __restrict__ H, float* __restrict__ agg, int n)
{
    __shared__ float lds_a[4][64];
    __shared__ int   lds_s[4][64];
    int wi   = threadIdx.x >> 6;
    int lane = threadIdx.x & 63;
    int w = blockIdx.x * 4 + wi;
    if (w >= n) return;

    int beg = rowptr[w];
    int end = rowptr[w + 1];
    int deg = end - beg;
    float adst = Adst[w];

    if (deg <= 64) {
        // ---- fast path: single gather, register softmax ----
        int   s = 0;
        float l = -3.4e38f;
        if (lane < deg) {
            s = col[beg + lane];
            float v = Asrc[s] + adst;
            l = v > 0.f ? v : NEG_SLOPE * v;
        }
        float m = l;
        #pragma unroll
        for (int o = 32; o; o >>= 1) m = fmaxf(m, __shfl_xor(m, o, 64));
        float ex = (lane < deg) ? __expf(l - m) : 0.f;
        float den = ex;
        #pragma unroll
        for (int o = 32; o; o >>= 1) den += __shfl_xor(den, o, 64);
        float alpha = ex / (den + 1e-16f);

        float a0 = 0.f, a1 = 0.f, a2 = 0.f, a3 = 0.f;
        int j = 0;
        for (; j + 4 <= deg; j += 4) {
            int   s0 = __shfl(s, j,     64), s1 = __shfl(s, j + 1, 64);
            int   s2 = __shfl(s, j + 2, 64), s3 = __shfl(s, j + 3, 64);
            float p0 = __shfl(alpha, j,     64), p1 = __shfl(alpha, j + 1, 64);
            float p2 = __shfl(alpha, j + 2, 64), p3 = __shfl(alpha, j + 3, 64);
            a0 += p0 * H[(size_t)s0 * 64 + lane];
            a1 += p1 * H[(size_t)s1 * 64 + lane];
            a2 += p2 * H[(size_t)s2 * 64 + lane];
            a3 += p3 * H[(size_t)s3 * 64 + lane];
        }
        for (; j < deg; j++) {
            int   sj = __shfl(s, j, 64);
            float pj = __shfl(alpha, j, 64);
            a0 += pj * H[(size_t)sj * 64 + lane];
        }
        agg[(size_t)w * 64 + lane] = (a0 + a1) + (a2 + a3);
        return;
    }

    // ---- generic path (deg > 64, rare) ----
    float m = -3.4e38f;
    for (int i = beg + lane; i < end; i += 64) {
        float l = Asrc[col[i]] + adst;
        l = l > 0.f ? l : NEG_SLOPE * l;
        m = fmaxf(m, l);
    }
    #pragma unroll
    for (int o = 32; o; o >>= 1) m = fmaxf(m, __shfl_xor(m, o, 64));

    float den = 0.f;
    for (int i = beg + lane; i < end; i += 64) {
        float l = Asrc[col[i]] + adst;
        l = l > 0.f ? l : NEG_SLOPE * l;
        den += __expf(l - m);
    }
    #pragma unroll
    for (int o = 32; o; o >>= 1) den += __shfl_xor(den, o, 64);
    float inv = 1.f / (den + 1e-16f);

    float acc = 0.f;
    for (int cbeg = beg; cbeg < end; cbeg += 64) {
        int cnt = min(64, end - cbeg);
        int i = cbeg + lane;
        if (lane < cnt) {
            int s = col[i];
            float l = Asrc[s] + adst;
            l = l > 0.f ? l : NEG_SLOPE * l;
            lds_a[wi][lane] = __expf(l - m) * inv;
            lds_s[wi][lane] = s;
        }
        for (int j = 0; j < cnt; j++) {
            acc += lds_a[wi][j] * H[(size_t)lds_s[wi][j] * 64 + lane];
        }
    }
    agg[(size_t)w * 64 + lane] = acc;
}

// ============================================================
// classifier: relu(agg + b2) @ Wc + bc -> log_softmax (C=2)
// ============================================================
__global__ __launch_bounds__(256) void classifier_k(
    const float* __restrict__ agg, const float* __restrict__ bias,
    const float* __restrict__ Wc, const float* __restrict__ bc,
    float* __restrict__ out, int n)
{
    __shared__ float Wcs[128], bs[64], bcs[2];
    int t = threadIdx.x;
    if (t < 128) Wcs[t] = Wc[t];
    if (t < 64) bs[t] = bias[t];
    if (t < 2) bcs[t] = bc[t];
    __syncthreads();

    int row = blockIdx.x * 256 + t;
    if (row >= n) return;
    const float* ap = agg + (size_t)row * 64;
    float z0 = bcs[0], z1 = bcs[1];
    #pragma unroll
    for (int k = 0; k < 64; k++) {
        float h = fmaxf(ap[k] + bs[k], 0.f);
        z0 += h * Wcs[2 * k];
        z1 += h * Wcs[2 * k + 1];
    }
    float m = fmaxf(z0, z1);
    float lse = m + logf(__expf(z0 - m) + __expf(z1 - m));
    out[(size_t)row * 2]     = z0 - lse;
    out[(size_t)row * 2 + 1] = z1 - lse;
}

extern "C" void kernel_launch(void* const* d_in, const int* in_sizes, int n_in,
                              void* d_out, int out_size, void* d_ws, size_t ws_size,
                              hipStream_t stream)
{
    const float* x   = (const float*)d_in[0];
    const int*   ei  = (const int*)d_in[1];
    const float* W1  = (const float*)d_in[2];
    const float* as1 = (const float*)d_in[3];
    const float* ad1 = (const float*)d_in[4];
    const float* b1  = (const float*)d_in[5];
    const float* W2  = (const float*)d_in[6];
    const float* as2 = (const float*)d_in[7];
    const float* ad2 = (const float*)d_in[8];
    const float* b2  = (const float*)d_in[9];
    const float* Wc  = (const float*)d_in[10];
    const float* bc  = (const float*)d_in[11];
    float* out = (float*)d_out;

    const int N  = in_sizes[0] / 64;   // 100000
    const int E  = in_sizes[1] / 2;    // 1200000
    const int EN = E + N;

    // workspace layout (all 4B elems):
    // h[N*64] | agg[N*64] | asrc[N] | adst[N] | deg[N] | partial[N] |
    // rowptr[N+1] | bsum[1024] | col[EN]
    // rank[EN] aliases agg (agg dead until first node_agg_k).
    float* h    = (float*)d_ws;
    float* agg  = h + (size_t)N * 64;
    float* asrc = agg + (size_t)N * 64;
    float* adst = asrc + N;
    int* deg     = (int*)(adst + N);
    int* partial = deg + N;
    int* rowptr  = partial + N;
    int* bsum    = rowptr + (N + 1);
    int* col     = bsum + 1024;
    int* rank    = (int*)agg;

    const int gN  = (N + 255) / 256;
    const int gE  = (EN + 255) / 256;
    const int gSc = (N + 1023) / 1024;
    const int gW  = (N + 3) / 4;

    // ---------------- CSR build (shared by both layers) ----------------
    hipMemsetAsync(deg, 0, (size_t)N * sizeof(int), stream);
    count_rank_k<<<gE, 256, 0, stream>>>(ei, deg, rank, E, EN);
    scan1_k<<<gSc, 256, 0, stream>>>(deg, partial, bsum, N);
    scan2_k<<<1, 256, 0, stream>>>(bsum, gSc);
    scan3_k<<<gN, 256, 0, stream>>>(partial, bsum, rowptr, N, EN);
    fill_k<<<gE, 256, 0, stream>>>(ei, rank, rowptr, col, E, EN);

    // ---------------- layer 1 ----------------
    gemm_attn<<<gN, 256, 0, stream>>>(x, W1, as1, ad1, b1, 0, h, asrc, adst, N);
    node_agg_k<<<gW, 256, 0, stream>>>(rowptr, col, asrc, adst, h, agg, N);

    // ---------------- layer 2 ----------------
    gemm_attn<<<gN, 256, 0, stream>>>(agg, W2, as2, ad2, b1, 1, h, asrc, adst, N);
    node_agg_k<<<gW, 256, 0, stream>>>(rowptr, col, asrc, adst, h, agg, N);

    // ---------------- classifier ----------------
    classifier_k<<<gN, 256, 0, stream>>>(agg, b2, Wc, bc, out, N);
}